// Round 7
// baseline (712.854 us; speedup 1.0000x reference)
//
#include <hip/hip_runtime.h>
#include <hip/hip_bf16.h>

typedef __bf16 bf16;
typedef __attribute__((ext_vector_type(8))) __bf16 bf16x8;
typedef __attribute__((ext_vector_type(4))) float f32x4;

constexpr int D_IN  = 512;
constexpr int D_HID = 256;
constexpr int D_OUT = 32;
constexpr int BM = 64;     // rows per block
constexpr int HCP = 40;    // Hc chunk-stride (bf16)
constexpr int SCAN_VPT  = 8;
constexpr int SCAN_SPAN = 2048;  // 256 threads * 8
constexpr int NSLICE = 8;        // XCD count: writer partitioning

// ---------------- prep: W1 -> W1T (bf16, [n][k]), W2 -> W2T (bf16, [n][k]) --
__global__ __launch_bounds__(256) void prep_kernel(
    const float* __restrict__ W1, const float* __restrict__ W2,
    bf16* __restrict__ W1T, bf16* __restrict__ W2T)
{
    int idx = blockIdx.x * 256 + threadIdx.x;
    if (idx < D_IN * D_HID) {
        int k = idx / D_HID, n = idx % D_HID;
        W1T[n * D_IN + k] = (bf16)W1[idx];
    }
    int j = idx - D_IN * D_HID;
    if (j >= 0 && j < D_HID * D_OUT) {
        int k = j / D_OUT, n = j % D_OUT;
        W2T[n * D_HID + k] = (bf16)W2[j];
    }
}

// ---------------- fused MLP: X = relu(feat@W1 + b1) @ W2 + b2 ---------------
// Round-7: GEMM1 reads B-fragments DIRECTLY from global W1T (256 KB, L2-hot
// on every XCD) — no LDS staging, no K-loop barriers, no vmcnt(0) drains.
// Same pattern GEMM2 already uses for W2T. The K-loop is a pure dataflow
// graph (loads + MFMAs) the compiler pipelines freely; waves never
// collectively stall. LDS = 5 KB Hc only -> high occupancy.
__global__ __launch_bounds__(256) void fused_mlp_kernel(
    const float* __restrict__ feat,
    const bf16* __restrict__ W1T, const bf16* __restrict__ W2T,
    const float* __restrict__ b1, const float* __restrict__ b2,
    float* __restrict__ X, int N)
{
    __shared__ __align__(16) bf16 Hc[BM * HCP];   // 5 KB

    const int tid  = threadIdx.x;
    const int wave = tid >> 6;
    const int lane = tid & 63;
    const int ln   = lane & 15;   // MFMA row/col index
    const int q    = lane >> 4;   // quad 0..3
    const int mw   = wave * 16;   // wave's row block within tile
    const int r0   = blockIdx.x * BM;

    f32x4 acc[16] = {};  // 16 n-tiles of 16x16 per wave (full D_HID)

    // A source: lane (q,ln) owns row mw+ln, k-slice q*8..q*8+7 (fragment layout)
    const long arow = (long)min(r0 + mw + ln, N - 1);
    const float* asrc = feat + arow * D_IN + q * 8;
    // B row base for this lane (row ln within each 16-row n-tile)
    const bf16* bsrc = W1T + (long)ln * D_IN + q * 8;

    #pragma unroll
    for (int s = 0; s < 8; ++s) {   // K in steps of 64 (2 MFMA k-halves)
        const int k0 = s * 64;

        // A fragments: direct global -> registers (HBM; the only cold data)
        bf16x8 af0, af1;
        {
            float4 f0 = *(const float4*)(asrc + k0);
            float4 f1 = *(const float4*)(asrc + k0 + 4);
            af0[0] = (bf16)f0.x; af0[1] = (bf16)f0.y; af0[2] = (bf16)f0.z; af0[3] = (bf16)f0.w;
            af0[4] = (bf16)f1.x; af0[5] = (bf16)f1.y; af0[6] = (bf16)f1.z; af0[7] = (bf16)f1.w;
            float4 f2 = *(const float4*)(asrc + k0 + 32);
            float4 f3 = *(const float4*)(asrc + k0 + 36);
            af1[0] = (bf16)f2.x; af1[1] = (bf16)f2.y; af1[2] = (bf16)f2.z; af1[3] = (bf16)f2.w;
            af1[4] = (bf16)f3.x; af1[5] = (bf16)f3.y; af1[6] = (bf16)f3.z; af1[7] = (bf16)f3.w;
        }

        // B fragments straight from L2-hot W1T; 16 independent MFMA chains
        #pragma unroll
        for (int t = 0; t < 16; ++t) {
            bf16x8 bfv = *(const bf16x8*)(bsrc + (long)t * 16 * D_IN + k0);
            acc[t] = __builtin_amdgcn_mfma_f32_16x16x32_bf16(af0, bfv, acc[t], 0, 0, 0);
        }
        #pragma unroll
        for (int t = 0; t < 16; ++t) {
            bf16x8 bfv = *(const bf16x8*)(bsrc + (long)t * 16 * D_IN + k0 + 32);
            acc[t] = __builtin_amdgcn_mfma_f32_16x16x32_bf16(af1, bfv, acc[t], 0, 0, 0);
        }
    }

    // GEMM2: X_tile = relu(h) @ W2, transposed chunkwise through Hc.
    // Chunk cc covers h cols 32cc..32cc+31 (acc tiles t=2cc, 2cc+1);
    // write -> sync -> read -> sync (LDS-only; verified round 5).
    f32x4 acc2[2] = {};
    #pragma unroll
    for (int cc = 0; cc < 8; ++cc) {
        #pragma unroll
        for (int tt = 0; tt < 2; ++tt) {
            int t = cc * 2 + tt;
            float bb = b1[t * 16 + ln];
            #pragma unroll
            for (int i = 0; i < 4; ++i) {
                int row = mw + q * 4 + i;
                float v = acc[t][i] + bb;
                Hc[row * HCP + tt * 16 + ln] = (bf16)fmaxf(v, 0.0f);
            }
        }
        __syncthreads();   // Hc chunk visible
        bf16x8 af2 = *(const bf16x8*)&Hc[(mw + ln) * HCP + q * 8];
        int kg = cc * 32 + q * 8;
        #pragma unroll
        for (int t2 = 0; t2 < 2; ++t2) {
            bf16x8 bfv = *(const bf16x8*)&W2T[(t2 * 16 + ln) * D_HID + kg];
            acc2[t2] = __builtin_amdgcn_mfma_f32_16x16x32_bf16(af2, bfv, acc2[t2], 0, 0, 0);
        }
        __syncthreads();   // before next chunk overwrites Hc
    }

    // Epilogue: X = acc2 + b2 (fp32)
    #pragma unroll
    for (int t = 0; t < 2; ++t) {
        int c = t * 16 + ln;
        float bb = b2[c];
        #pragma unroll
        for (int i = 0; i < 4; ++i) {
            int row = r0 + mw + q * 4 + i;
            if (row < N) X[row * D_OUT + c] = acc2[t][i] + bb;
        }
    }
}

// ---------------- CSR build: histogram -> scan -> reorder -------------------
// hist XCD-sliced: all atomics to a row region issue from one XCD.
__global__ __launch_bounds__(256) void hist_kernel(
    const int* __restrict__ Arow, int* __restrict__ counts, int E, int rps)
{
    int b = blockIdx.x;
    int slice = b & (NSLICE - 1);
    int e = (b >> 3) * 256 + threadIdx.x;
    if (e >= E) return;
    int r = Arow[e];
    if ((unsigned)(r - slice * rps) >= (unsigned)rps) return;
    atomicAdd(&counts[r], 1);
}

__global__ __launch_bounds__(256) void scanA_kernel(
    const int* __restrict__ counts, int* __restrict__ offs,
    int* __restrict__ partials, int N)
{
    __shared__ int lds[256];
    int t = threadIdx.x;
    int base = blockIdx.x * SCAN_SPAN + t * SCAN_VPT;
    int v[SCAN_VPT];
    int tsum = 0;
    #pragma unroll
    for (int j = 0; j < SCAN_VPT; ++j) {
        v[j] = (base + j < N) ? counts[base + j] : 0;
        tsum += v[j];
    }
    lds[t] = tsum;
    __syncthreads();
    for (int d = 1; d < 256; d <<= 1) {
        int x = (t >= d) ? lds[t - d] : 0;
        __syncthreads();
        lds[t] += x;
        __syncthreads();
    }
    int run = lds[t] - tsum;
    #pragma unroll
    for (int j = 0; j < SCAN_VPT; ++j) {
        if (base + j < N) offs[base + j] = run;
        run += v[j];
    }
    if (t == 255) partials[blockIdx.x] = lds[255];
}

__global__ __launch_bounds__(256) void scanB_kernel(int* __restrict__ partials, int nb)
{
    __shared__ int lds[256];
    int t = threadIdx.x;
    int v = (t < nb) ? partials[t] : 0;
    lds[t] = v;
    __syncthreads();
    for (int d = 1; d < 256; d <<= 1) {
        int x = (t >= d) ? lds[t - d] : 0;
        __syncthreads();
        lds[t] += x;
        __syncthreads();
    }
    if (t < nb) partials[t] = lds[t] - v;
}

__global__ __launch_bounds__(256) void scanC_kernel(
    int* __restrict__ offs, const int* __restrict__ partials,
    int* __restrict__ cursor, int N)
{
    int i = blockIdx.x * 256 + threadIdx.x;
    if (i < N) {
        int o = offs[i] + partials[i / SCAN_SPAN];
        offs[i] = o;
        cursor[i] = o;
    }
}

// ---------------- reorder, XCD-writer-partitioned ---------------------------
// Frontier per slice = 1.6 MB < 4 MiB per-XCD L2 -> full-line evictions.
__global__ __launch_bounds__(256) void reorder_kernel(
    const int* __restrict__ Arow, const int* __restrict__ Acol,
    const float* __restrict__ Adata, int* __restrict__ cursor,
    int2* __restrict__ pairs, int E, int rps)
{
    int b = blockIdx.x;
    int slice = b & (NSLICE - 1);
    int e = (b >> 3) * 256 + threadIdx.x;
    if (e >= E) return;
    int r = Arow[e];
    if ((unsigned)(r - slice * rps) >= (unsigned)rps) return;
    int p = atomicAdd(&cursor[r], 1);
    int2 pk;
    pk.x = Acol[e];
    pk.y = __float_as_int(Adata[e]);
    pairs[p] = pk;  // single 8B store; frontier lines owned by one XCD
}

// ---------------- reduce: one wave per row, 8 edges in flight ---------------
__global__ __launch_bounds__(256) void reduce_kernel(
    const int* __restrict__ offs, const int* __restrict__ counts,
    const int2* __restrict__ pairs, const float* __restrict__ X,
    float* __restrict__ out, int N)
{
    int w    = threadIdx.x >> 6;
    int lane = threadIdx.x & 63;
    int r    = blockIdx.x * 4 + w;
    if (r >= N) return;
    int slot = lane >> 3;    // edge slot 0..7
    int dg   = lane & 7;     // dim group: dims 4*dg..4*dg+3
    int off  = offs[r];
    int deg  = counts[r];
    f32x4 acc = {0.0f, 0.0f, 0.0f, 0.0f};
    for (int i = slot; i < deg; i += 8) {
        int2  pk = pairs[off + i];       // broadcast across the 8 dg lanes
        float a  = __int_as_float(pk.y);
        f32x4 x  = *(const f32x4*)(X + (long)pk.x * D_OUT + dg * 4);
        acc += a * x;
    }
    // butterfly over slots (strides 8,16,32)
    #pragma unroll
    for (int d = 8; d < 64; d <<= 1) {
        acc[0] += __shfl_xor(acc[0], d, 64);
        acc[1] += __shfl_xor(acc[1], d, 64);
        acc[2] += __shfl_xor(acc[2], d, 64);
        acc[3] += __shfl_xor(acc[3], d, 64);
    }
    if (slot == 0) *(f32x4*)(out + (long)r * D_OUT + dg * 4) = acc;
}

// ---------------- fallback scatter (if ws too small) ------------------------
__global__ __launch_bounds__(256) void scatter_kernel(
    const float* __restrict__ Adata, const int* __restrict__ Arow,
    const int* __restrict__ Acol, const float* __restrict__ X,
    float* __restrict__ out, int E)
{
    int idx = blockIdx.x * 256 + threadIdx.x;
    int e = idx >> 3;
    int g = idx & 7;
    if (e >= E) return;
    int   col = Acol[e];
    int   row = Arow[e];
    float a   = Adata[e];
    float4 x = *(const float4*)(X + (long)col * D_OUT + g * 4);
    float* o = out + (long)row * D_OUT + g * 4;
    unsafeAtomicAdd(o + 0, a * x.x);
    unsafeAtomicAdd(o + 1, a * x.y);
    unsafeAtomicAdd(o + 2, a * x.z);
    unsafeAtomicAdd(o + 3, a * x.w);
}

// ---------------- launch ----------------------------------------------------
extern "C" void kernel_launch(void* const* d_in, const int* in_sizes, int n_in,
                              void* d_out, int out_size, void* d_ws, size_t ws_size,
                              hipStream_t stream)
{
    const float* feat  = (const float*)d_in[0];
    const float* Adata = (const float*)d_in[1];
    const float* W1    = (const float*)d_in[2];
    const float* b1    = (const float*)d_in[3];
    const float* W2    = (const float*)d_in[4];
    const float* b2    = (const float*)d_in[5];
    const int*   Arow  = (const int*)d_in[6];
    const int*   Acol  = (const int*)d_in[7];

    const int N = in_sizes[0] / D_IN;
    const int E = in_sizes[1];

    // --- workspace carve-out (256B aligned segments) ---
    char* p = (char*)d_ws;
    auto alloc = [&](size_t bytes) {
        char* q = p;
        p += (bytes + 255) & ~(size_t)255;
        return q;
    };
    float* X       = (float*)alloc((size_t)N * D_OUT * sizeof(float));
    bf16*  W1T     = (bf16*) alloc((size_t)D_IN * D_HID * sizeof(bf16));
    bf16*  W2T     = (bf16*) alloc((size_t)D_HID * D_OUT * sizeof(bf16));
    int*   counts  = (int*)  alloc((size_t)N * sizeof(int));
    int*   offs    = (int*)  alloc((size_t)N * sizeof(int));
    int*   cursor  = (int*)  alloc((size_t)N * sizeof(int));
    int*   partials= (int*)  alloc(256 * sizeof(int));
    int2*  pairs   = (int2*) alloc((size_t)E * sizeof(int2));
    size_t need = (size_t)(p - (char*)d_ws);
    const bool use_csr = (need <= ws_size);

    float* out = (float*)d_out;

    int prep_elems = D_IN * D_HID + D_HID * D_OUT;
    prep_kernel<<<(prep_elems + 255) / 256, 256, 0, stream>>>(W1, W2, W1T, W2T);

    fused_mlp_kernel<<<(N + BM - 1) / BM, 256, 0, stream>>>(
        feat, W1T, W2T, b1, b2, X, N);

    if (use_csr) {
        hipMemsetAsync(counts, 0, (size_t)N * sizeof(int), stream);
        int rps = (N + NSLICE - 1) / NSLICE;
        hist_kernel<<<NSLICE * ((E + 255) / 256), 256, 0, stream>>>(
            Arow, counts, E, rps);
        int nb = (N + SCAN_SPAN - 1) / SCAN_SPAN;   // 49 for N=100000 (<=256)
        scanA_kernel<<<nb, 256, 0, stream>>>(counts, offs, partials, N);
        scanB_kernel<<<1, 256, 0, stream>>>(partials, nb);
        scanC_kernel<<<(N + 255) / 256, 256, 0, stream>>>(offs, partials, cursor, N);
        reorder_kernel<<<NSLICE * ((E + 255) / 256), 256, 0, stream>>>(
            Arow, Acol, Adata, cursor, pairs, E, rps);
        reduce_kernel<<<(N + 3) / 4, 256, 0, stream>>>(
            offs, counts, pairs, X, out, N);
    } else {
        hipMemsetAsync(out, 0, (size_t)out_size * sizeof(float), stream);
        long scatter_threads = (long)E * 8;
        scatter_kernel<<<(scatter_threads + 255) / 256, 256, 0, stream>>>(
            Adata, Arow, Acol, X, out, E);
    }
}

// Round 8
// 547.955 us; speedup vs baseline: 1.3009x; 1.3009x over previous
//
#include <hip/hip_runtime.h>
#include <hip/hip_bf16.h>

typedef __bf16 bf16;
typedef __attribute__((ext_vector_type(8))) __bf16 bf16x8;
typedef __attribute__((ext_vector_type(4))) float f32x4;

constexpr int D_IN  = 512;
constexpr int D_HID = 256;
constexpr int D_OUT = 32;
constexpr int BM = 64;     // rows per block
constexpr int BK = 64;     // K chunk (two 16x16x32 MFMA deep)
constexpr int HCP = 40;    // Hc chunk-stride (bf16)
constexpr int SCAN_VPT  = 8;
constexpr int SCAN_SPAN = 2048;  // 256 threads * 8
constexpr int NSLICE = 8;        // XCD count: writer partitioning
constexpr int CHB = 1024;        // grid-stride span (blocks/slice) for hist/reorder

#define GLOBAL_AS(p) ((const __attribute__((address_space(1))) void*)(p))
#define LDS_AS(p)    ((__attribute__((address_space(3))) void*)(p))

// ---------------- prep: W1 -> W1T (bf16, [n][k]), W2 -> W2T (bf16, [n][k]) --
__global__ __launch_bounds__(256) void prep_kernel(
    const float* __restrict__ W1, const float* __restrict__ W2,
    bf16* __restrict__ W1T, bf16* __restrict__ W2T)
{
    int idx = blockIdx.x * 256 + threadIdx.x;
    if (idx < D_IN * D_HID) {
        int k = idx / D_HID, n = idx % D_HID;
        W1T[n * D_IN + k] = (bf16)W1[idx];
    }
    int j = idx - D_IN * D_HID;
    if (j >= 0 && j < D_HID * D_OUT) {
        int k = j / D_OUT, n = j % D_OUT;
        W2T[n * D_HID + k] = (bf16)W2[j];
    }
}

// ---------------- fused MLP: X = relu(feat@W1 + b1) @ W2 + b2 ---------------
// Round-8: same verified sync topology (stage -> sync -> MFMA -> sync), but
// 8 waves/block (512 thr); wave (s=w>>1, h=w&1) owns rows s*16..+15 and hid
// cols h*128..+127 -> acc[8] (32 AGPR vs 64). Unified regs ~110 -> 4 waves/
// SIMD -> 2 blocks/CU resident (16 waves, 50%) vs round-5's ~2-3 waves/SIMD.
// Staging also 2x wider (512 threads x 4 chunks). LDS unchanged (32 KB).
__global__ __launch_bounds__(512, 4) void fused_mlp_kernel(
    const float* __restrict__ feat,
    const bf16* __restrict__ W1T, const bf16* __restrict__ W2T,
    const float* __restrict__ b1, const float* __restrict__ b2,
    float* __restrict__ X, int N)
{
    // Bsm: [D_HID][BK] bf16 = 32 KB (staging; dead after K-loop)
    // Hc : [BM][HCP]  bf16 = 5 KB, aliases Bsm
    __shared__ __align__(16) char smem[D_HID * BK * sizeof(bf16)];
    bf16* Bsm = (bf16*)smem;
    bf16* Hc  = (bf16*)smem;

    const int tid  = threadIdx.x;
    const int w    = tid >> 6;    // wave 0..7
    const int lane = tid & 63;
    const int ln   = lane & 15;   // MFMA row/col index
    const int q    = lane >> 4;   // quad 0..3
    const int s    = w >> 1;      // row stripe 0..3
    const int h    = w & 1;       // hid half 0..1
    const int mw   = s * 16;      // stripe's row offset in tile
    const int r0   = blockIdx.x * BM;

    f32x4 acc[8] = {};  // 8 n-tiles of 16x16: hid cols h*128 + t*16 + ln

    // A source: lane (q,ln) owns row mw+ln, k-slice q*8..q*8+7
    const long arow = (long)min(r0 + mw + ln, N - 1);
    const float* asrc = feat + arow * D_IN + q * 8;

    for (int k0 = 0; k0 < D_IN; k0 += BK) {   // 8 steps
        // async stage B tile [256][64] from W1T. LDS dest linear (16B*c);
        // GLOBAL slot permuted: phys slot p of row r holds logical p^(r&7).
        #pragma unroll
        for (int i = 0; i < 4; ++i) {
            int c  = i * 512 + w * 64 + lane;           // 0..2047
            int sl = (c & 7) ^ ((c >> 3) & 7);
            const bf16* gsrc = W1T + ((c >> 3) * D_IN + k0 + sl * 8);
            bf16* lbase = Bsm + (i * 512 + w * 64) * 8;  // wave-uniform
            __builtin_amdgcn_global_load_lds(GLOBAL_AS(gsrc), LDS_AS(lbase), 16, 0, 0);
        }

        // A fragments for both 32-wide k-halves: direct global -> registers
        bf16x8 af0, af1;
        {
            float4 f0 = *(const float4*)(asrc + k0);
            float4 f1 = *(const float4*)(asrc + k0 + 4);
            af0[0] = (bf16)f0.x; af0[1] = (bf16)f0.y; af0[2] = (bf16)f0.z; af0[3] = (bf16)f0.w;
            af0[4] = (bf16)f1.x; af0[5] = (bf16)f1.y; af0[6] = (bf16)f1.z; af0[7] = (bf16)f1.w;
            float4 f2 = *(const float4*)(asrc + k0 + 32);
            float4 f3 = *(const float4*)(asrc + k0 + 36);
            af1[0] = (bf16)f2.x; af1[1] = (bf16)f2.y; af1[2] = (bf16)f2.z; af1[3] = (bf16)f2.w;
            af1[4] = (bf16)f3.x; af1[5] = (bf16)f3.y; af1[6] = (bf16)f3.z; af1[7] = (bf16)f3.w;
        }

        __syncthreads();   // drains global_load_lds (compiler vmcnt(0) pre-barrier)

        const int psl0 = q ^ (ln & 7);          // kk=0 phys slot
        #pragma unroll
        for (int t = 0; t < 8; ++t) {
            int row = h * 128 + t * 16 + ln;    // row&7 == ln&7
            bf16x8 bfv = *(const bf16x8*)&Bsm[row * BK + psl0 * 8];
            acc[t] = __builtin_amdgcn_mfma_f32_16x16x32_bf16(af0, bfv, acc[t], 0, 0, 0);
        }
        const int psl1 = (4 + q) ^ (ln & 7);    // kk=1 phys slot
        #pragma unroll
        for (int t = 0; t < 8; ++t) {
            int row = h * 128 + t * 16 + ln;
            bf16x8 bfv = *(const bf16x8*)&Bsm[row * BK + psl1 * 8];
            acc[t] = __builtin_amdgcn_mfma_f32_16x16x32_bf16(af1, bfv, acc[t], 0, 0, 0);
        }
        __syncthreads();   // protect Bsm for next step's staging
    }

    // GEMM2: X_tile = relu(h) @ W2, transposed chunkwise through Hc.
    // Chunk cc covers h-cols 32cc..32cc+31 = global tiles Tg=2cc,2cc+1,
    // owned by waves with h == cc>>2. Each wave computes output n-tile t2=h.
    f32x4 acc2 = {};
    #pragma unroll
    for (int cc = 0; cc < 8; ++cc) {
        if (h == (cc >> 2)) {
            #pragma unroll
            for (int tt = 0; tt < 2; ++tt) {
                int Tg = cc * 2 + tt;          // global hid tile 0..15
                int t  = Tg - h * 8;           // local acc index 0..7
                float bb = b1[Tg * 16 + ln];
                #pragma unroll
                for (int i = 0; i < 4; ++i) {
                    int row = mw + q * 4 + i;
                    float v = acc[t][i] + bb;
                    Hc[row * HCP + tt * 16 + ln] = (bf16)fmaxf(v, 0.0f);
                }
            }
        }
        __syncthreads();   // Hc chunk visible (first iter also: Bsm reads done)
        bf16x8 af2 = *(const bf16x8*)&Hc[(mw + ln) * HCP + q * 8];
        int kg = cc * 32 + q * 8;
        bf16x8 bfv = *(const bf16x8*)&W2T[(h * 16 + ln) * D_HID + kg];
        acc2 = __builtin_amdgcn_mfma_f32_16x16x32_bf16(af2, bfv, acc2, 0, 0, 0);
        __syncthreads();   // before next chunk overwrites Hc
    }

    // Epilogue: X = acc2 + b2 (fp32); wave (s,h) owns rows mw.., cols h*16..
    {
        int c = h * 16 + ln;
        float bb = b2[c];
        #pragma unroll
        for (int i = 0; i < 4; ++i) {
            int row = r0 + mw + q * 4 + i;
            if (row < N) X[row * D_OUT + c] = acc2[i] + bb;
        }
    }
}

// ---------------- CSR build: histogram -> scan -> reorder -------------------
// hist XCD-sliced, grid-stride (compact grid: NSLICE*CHB blocks).
__global__ __launch_bounds__(256) void hist_kernel(
    const int* __restrict__ Arow, int* __restrict__ counts, int E, int rps)
{
    int slice = blockIdx.x & (NSLICE - 1);
    int nch = (E + 255) / 256;
    for (int ch = blockIdx.x >> 3; ch < nch; ch += CHB) {
        int e = ch * 256 + threadIdx.x;
        if (e < E) {
            int r = Arow[e];
            if ((unsigned)(r - slice * rps) < (unsigned)rps)
                atomicAdd(&counts[r], 1);
        }
    }
}

__global__ __launch_bounds__(256) void scanA_kernel(
    const int* __restrict__ counts, int* __restrict__ offs,
    int* __restrict__ partials, int N)
{
    __shared__ int lds[256];
    int t = threadIdx.x;
    int base = blockIdx.x * SCAN_SPAN + t * SCAN_VPT;
    int v[SCAN_VPT];
    int tsum = 0;
    #pragma unroll
    for (int j = 0; j < SCAN_VPT; ++j) {
        v[j] = (base + j < N) ? counts[base + j] : 0;
        tsum += v[j];
    }
    lds[t] = tsum;
    __syncthreads();
    for (int d = 1; d < 256; d <<= 1) {
        int x = (t >= d) ? lds[t - d] : 0;
        __syncthreads();
        lds[t] += x;
        __syncthreads();
    }
    int run = lds[t] - tsum;
    #pragma unroll
    for (int j = 0; j < SCAN_VPT; ++j) {
        if (base + j < N) offs[base + j] = run;
        run += v[j];
    }
    if (t == 255) partials[blockIdx.x] = lds[255];
}

__global__ __launch_bounds__(256) void scanB_kernel(int* __restrict__ partials, int nb)
{
    __shared__ int lds[256];
    int t = threadIdx.x;
    int v = (t < nb) ? partials[t] : 0;
    lds[t] = v;
    __syncthreads();
    for (int d = 1; d < 256; d <<= 1) {
        int x = (t >= d) ? lds[t - d] : 0;
        __syncthreads();
        lds[t] += x;
        __syncthreads();
    }
    if (t < nb) partials[t] = lds[t] - v;
}

__global__ __launch_bounds__(256) void scanC_kernel(
    int* __restrict__ offs, const int* __restrict__ partials,
    int* __restrict__ cursor, int N)
{
    int i = blockIdx.x * 256 + threadIdx.x;
    if (i < N) {
        int o = offs[i] + partials[i / SCAN_SPAN];
        offs[i] = o;
        cursor[i] = o;
    }
}

// ---------------- reorder, XCD-writer-partitioned, grid-stride --------------
// Frontier per slice = 1.6 MB < 4 MiB per-XCD L2 -> full-line evictions.
__global__ __launch_bounds__(256) void reorder_kernel(
    const int* __restrict__ Arow, const int* __restrict__ Acol,
    const float* __restrict__ Adata, int* __restrict__ cursor,
    int2* __restrict__ pairs, int E, int rps)
{
    int slice = blockIdx.x & (NSLICE - 1);
    int nch = (E + 255) / 256;
    for (int ch = blockIdx.x >> 3; ch < nch; ch += CHB) {
        int e = ch * 256 + threadIdx.x;
        if (e < E) {
            int r = Arow[e];
            if ((unsigned)(r - slice * rps) < (unsigned)rps) {
                int p = atomicAdd(&cursor[r], 1);
                int2 pk;
                pk.x = Acol[e];
                pk.y = __float_as_int(Adata[e]);
                pairs[p] = pk;  // 8B store; frontier lines owned by one XCD
            }
        }
    }
}

// ---------------- reduce: one wave per row, grid-stride ---------------------
__global__ __launch_bounds__(256) void reduce_kernel(
    const int* __restrict__ offs, const int* __restrict__ counts,
    const int2* __restrict__ pairs, const float* __restrict__ X,
    float* __restrict__ out, int N, int span)
{
    int w    = threadIdx.x >> 6;
    int lane = threadIdx.x & 63;
    int slot = lane >> 3;    // edge slot 0..7
    int dg   = lane & 7;     // dim group: dims 4*dg..4*dg+3
    for (int r = blockIdx.x * 4 + w; r < N; r += span) {
        int off  = offs[r];
        int deg  = counts[r];
        f32x4 acc = {0.0f, 0.0f, 0.0f, 0.0f};
        for (int i = slot; i < deg; i += 8) {
            int2  pk = pairs[off + i];       // broadcast across the 8 dg lanes
            float a  = __int_as_float(pk.y);
            f32x4 x  = *(const f32x4*)(X + (long)pk.x * D_OUT + dg * 4);
            acc += a * x;
        }
        #pragma unroll
        for (int d = 8; d < 64; d <<= 1) {
            acc[0] += __shfl_xor(acc[0], d, 64);
            acc[1] += __shfl_xor(acc[1], d, 64);
            acc[2] += __shfl_xor(acc[2], d, 64);
            acc[3] += __shfl_xor(acc[3], d, 64);
        }
        if (slot == 0) *(f32x4*)(out + (long)r * D_OUT + dg * 4) = acc;
    }
}

// ---------------- fallback scatter (if ws too small) ------------------------
__global__ __launch_bounds__(256) void scatter_kernel(
    const float* __restrict__ Adata, const int* __restrict__ Arow,
    const int* __restrict__ Acol, const float* __restrict__ X,
    float* __restrict__ out, int E)
{
    int idx = blockIdx.x * 256 + threadIdx.x;
    int e = idx >> 3;
    int g = idx & 7;
    if (e >= E) return;
    int   col = Acol[e];
    int   row = Arow[e];
    float a   = Adata[e];
    float4 x = *(const float4*)(X + (long)col * D_OUT + g * 4);
    float* o = out + (long)row * D_OUT + g * 4;
    unsafeAtomicAdd(o + 0, a * x.x);
    unsafeAtomicAdd(o + 1, a * x.y);
    unsafeAtomicAdd(o + 2, a * x.z);
    unsafeAtomicAdd(o + 3, a * x.w);
}

// ---------------- launch ----------------------------------------------------
extern "C" void kernel_launch(void* const* d_in, const int* in_sizes, int n_in,
                              void* d_out, int out_size, void* d_ws, size_t ws_size,
                              hipStream_t stream)
{
    const float* feat  = (const float*)d_in[0];
    const float* Adata = (const float*)d_in[1];
    const float* W1    = (const float*)d_in[2];
    const float* b1    = (const float*)d_in[3];
    const float* W2    = (const float*)d_in[4];
    const float* b2    = (const float*)d_in[5];
    const int*   Arow  = (const int*)d_in[6];
    const int*   Acol  = (const int*)d_in[7];

    const int N = in_sizes[0] / D_IN;
    const int E = in_sizes[1];

    // --- workspace carve-out (256B aligned segments) ---
    char* p = (char*)d_ws;
    auto alloc = [&](size_t bytes) {
        char* q = p;
        p += (bytes + 255) & ~(size_t)255;
        return q;
    };
    float* X       = (float*)alloc((size_t)N * D_OUT * sizeof(float));
    bf16*  W1T     = (bf16*) alloc((size_t)D_IN * D_HID * sizeof(bf16));
    bf16*  W2T     = (bf16*) alloc((size_t)D_HID * D_OUT * sizeof(bf16));
    int*   counts  = (int*)  alloc((size_t)N * sizeof(int));
    int*   offs    = (int*)  alloc((size_t)N * sizeof(int));
    int*   cursor  = (int*)  alloc((size_t)N * sizeof(int));
    int*   partials= (int*)  alloc(256 * sizeof(int));
    int2*  pairs   = (int2*) alloc((size_t)E * sizeof(int2));
    size_t need = (size_t)(p - (char*)d_ws);
    const bool use_csr = (need <= ws_size);

    float* out = (float*)d_out;

    int prep_elems = D_IN * D_HID + D_HID * D_OUT;
    prep_kernel<<<(prep_elems + 255) / 256, 256, 0, stream>>>(W1, W2, W1T, W2T);

    fused_mlp_kernel<<<(N + BM - 1) / BM, 512, 0, stream>>>(
        feat, W1T, W2T, b1, b2, X, N);

    if (use_csr) {
        hipMemsetAsync(counts, 0, (size_t)N * sizeof(int), stream);
        int rps = (N + NSLICE - 1) / NSLICE;
        hist_kernel<<<NSLICE * CHB, 256, 0, stream>>>(Arow, counts, E, rps);
        int nb = (N + SCAN_SPAN - 1) / SCAN_SPAN;   // 49 for N=100000 (<=256)
        scanA_kernel<<<nb, 256, 0, stream>>>(counts, offs, partials, N);
        scanB_kernel<<<1, 256, 0, stream>>>(partials, nb);
        scanC_kernel<<<(N + 255) / 256, 256, 0, stream>>>(offs, partials, cursor, N);
        reorder_kernel<<<NSLICE * CHB, 256, 0, stream>>>(
            Arow, Acol, Adata, cursor, pairs, E, rps);
        int rblocks = 4096;
        reduce_kernel<<<rblocks, 256, 0, stream>>>(
            offs, counts, pairs, X, out, N, rblocks * 4);
    } else {
        hipMemsetAsync(out, 0, (size_t)out_size * sizeof(float), stream);
        long scatter_threads = (long)E * 8;
        scatter_kernel<<<(scatter_threads + 255) / 256, 256, 0, stream>>>(
            Adata, Arow, Acol, X, out, E);
    }
}